// Round 11
// baseline (1048.057 us; speedup 1.0000x reference)
//
#include <hip/hip_runtime.h>

// ConvLSTM2D x2, 4-step temporal blocking, 5 launches, FULLY STATIC waves.
// Launch j: L1 computes t=4j..4j+3 (j=0..3); L2 computes t=4j-4..4j-1 (j=1..4).
// Block owns rows y0,y0+1; window rows y0-4..y0+5 in LDS. Every step computes
// window rows rw1..8 (trapezoid edges are garbage but never read by valid rows;
// own rows valid at every step). Wave unit FIXED: (row=wid>>1, fh=wid&1).
// mp unrolled with per-mp acc (32 regs); h@t buffered in regs, written to hbuf
// after barrier (removes WAR). c window in LDS (6 rows). No register weight
// arrays, no helper structs -> no scratch spill.

typedef __bf16 bf16x8 __attribute__((ext_vector_type(8)));
typedef float f32x4 __attribute__((ext_vector_type(4)));

#define WPK_ELEMS 73728   // per layer: 18 kchunks * 8 ntiles * 64 lanes * 8
#define PLANE 524288      // 4*64*64*32 elems per plane

__device__ __forceinline__ float fsigmoid(float z) {
    return 1.0f / (1.0f + __expf(-z));
}
__device__ __forceinline__ float ftanh(float z) {
    z = fminf(15.0f, fmaxf(-15.0f, z));
    float e = __expf(2.0f * z);
    return (e - 1.0f) / (e + 1.0f);
}

__global__ __launch_bounds__(256) void pack_weights(
    const float* __restrict__ wk1, const float* __restrict__ wr1,
    const float* __restrict__ wk2, const float* __restrict__ wr2,
    __bf16* __restrict__ wpk)
{
    int i = blockIdx.x * 256 + threadIdx.x;
    if (i >= 2 * WPK_ELEMS) return;
    int layer = i / WPK_ELEMS;
    int r = i - layer * WPK_ELEMS;
    int j2 = r & 7;
    int L  = (r >> 3) & 63;
    int nt = (r >> 9) & 7;
    int cix = r >> 12;
    int tap = cix >> 1, src = cix & 1;
    int s = ((L >> 4) << 3) + j2;
    int gate = nt & 3;
    int f = ((nt >> 2) << 4) + (L & 15);
    int n = (gate << 5) + f;
    const float* w = layer ? (src ? wr2 : wk2) : (src ? wr1 : wk1);
    wpk[i] = (__bf16)w[(tap * 32 + s) * 128 + n];
}

__device__ __forceinline__ bf16x8 cvt8(const float* p) {
    const float4 f0 = *(const float4*)p;
    const float4 f1 = *(const float4*)(p + 4);
    bf16x8 v;
    v[0] = (__bf16)f0.x; v[1] = (__bf16)f0.y;
    v[2] = (__bf16)f0.z; v[3] = (__bf16)f0.w;
    v[4] = (__bf16)f1.x; v[5] = (__bf16)f1.y;
    v[6] = (__bf16)f1.z; v[7] = (__bf16)f1.w;
    return v;
}

#define MFMA8(A0, A1, WP)                                                                 \
    acc[0][0] = __builtin_amdgcn_mfma_f32_16x16x32_bf16(A0, WP[0],   acc[0][0], 0, 0, 0); \
    acc[0][1] = __builtin_amdgcn_mfma_f32_16x16x32_bf16(A0, WP[64],  acc[0][1], 0, 0, 0); \
    acc[0][2] = __builtin_amdgcn_mfma_f32_16x16x32_bf16(A0, WP[128], acc[0][2], 0, 0, 0); \
    acc[0][3] = __builtin_amdgcn_mfma_f32_16x16x32_bf16(A0, WP[192], acc[0][3], 0, 0, 0); \
    acc[1][0] = __builtin_amdgcn_mfma_f32_16x16x32_bf16(A1, WP[0],   acc[1][0], 0, 0, 0); \
    acc[1][1] = __builtin_amdgcn_mfma_f32_16x16x32_bf16(A1, WP[64],  acc[1][1], 0, 0, 0); \
    acc[1][2] = __builtin_amdgcn_mfma_f32_16x16x32_bf16(A1, WP[128], acc[1][2], 0, 0, 0); \
    acc[1][3] = __builtin_amdgcn_mfma_f32_16x16x32_bf16(A1, WP[192], acc[1][3], 0, 0, 0);

__global__ __launch_bounds__(1024, 4) void clstm_s4(
    const float* __restrict__ x,
    const __bf16* __restrict__ wpk1, const __bf16* __restrict__ wpk2,
    const float* __restrict__ bias1, const float* __restrict__ bias2,
    __bf16* __restrict__ h1buf,       // 8 planes, t%8
    __bf16* __restrict__ h2buf,       // 2 parity planes (by launch j)
    float* __restrict__ c1,           // 2 parity planes (by launch j)
    float* __restrict__ c2,
    float* __restrict__ out, int j)
{
    __shared__ __bf16 xbuf[10 * 66 * 36];   // input-conv src window (restaged/step)
    __shared__ __bf16 hbuf[10 * 66 * 36];   // h window, in-place across steps
    __shared__ float  cbuf[6 * 64 * 32];    // c window rows rw2..7

    const int blk = blockIdx.x;
    const int xcd = blk & 7;
    const int rest = blk >> 3;
    const int layer = rest >> 4;
    if (layer ? (j < 1) : (j > 3)) return;
    const int grp = xcd * 16 + (rest & 15);  // XCD-contiguous rows
    const int T0 = layer ? 4 * (j - 1) : 4 * j;
    const int R = grp << 1;
    const int b = R >> 6, y0 = R & 63;
    const bool firstT = (T0 == 0);

    const int tid = threadIdx.x;
    const int wid = tid >> 6, L = tid & 63;
    const int c = L & 15, q = L >> 4, q8 = q * 8;
    const int row = wid >> 1;                // 0..7; window row rw=row+1
    const int fh = wid & 1;
    const int f = fh * 16 + c;
    const int yy = y0 - 3 + row;
    const bool rv = ((unsigned)yy < 64u);
    const bool own = (row == 3 || row == 4); // yy = y0 or y0+1 (always in range)
    const int crow = row - 1;                // cbuf row for rw2..7
    const bool cbv = ((unsigned)crow < 6u);

    const bf16x8* wpkv = (const bf16x8*)(layer ? wpk2 : wpk1);
    const float* bias = layer ? bias2 : bias1;
    float bv[4];
    #pragma unroll
    for (int g = 0; g < 4; ++g) bv[g] = bias[g * 32 + f];

    const float* cglob = (layer ? c2 : c1) + (size_t)((j - 1) & 1) * PLANE;
    float* cw = (layer ? c2 : c1) + (size_t)(j & 1) * PLANE;
    __bf16* h2w = h2buf + (size_t)(j & 1) * PLANE;
    const size_t gbase = ((size_t)(b * 64 + (rv ? yy : 0)) * 64) * 32;

    for (int s = 0; s < 4; ++s) {
        const int t = T0 + s;

        // ---- stage xbuf rows y0-4..y0+5 from x@t (L1) or h1@t (L2) ----
        {
            const float*  xs = x + (size_t)(b * 16 + t) * 131072;
            const __bf16* hs = h1buf + (size_t)(t & 7) * PLANE;
            for (int i = tid; i < 2640; i += 1024) {
                const int g = i & 3, rc2 = i >> 2;
                const int cc = rc2 % 66, rw = rc2 / 66;
                const int yr = y0 - 4 + rw, xc = cc - 1;
                bf16x8 v = {};
                if ((unsigned)yr < 64u && (unsigned)xc < 64u) {
                    if (layer) v = *(const bf16x8*)(hs + (((size_t)(b * 64 + yr)) * 64 + xc) * 32 + g * 8);
                    else       v = cvt8(xs + (((size_t)yr * 64 + xc) * 32 + g * 8));
                }
                *(bf16x8*)(xbuf + (rw * 66 + cc) * 36 + g * 8) = v;
            }
        }
        // ---- s=0: stage hbuf (h@T0-1) or zero it ----
        if (s == 0) {
            if (!firstT) {
                const __bf16* rs = layer ? (h2buf + (size_t)((j - 1) & 1) * PLANE)
                                         : (h1buf + (size_t)((T0 - 1) & 7) * PLANE);
                for (int i = tid; i < 2640; i += 1024) {
                    const int g = i & 3, rc2 = i >> 2;
                    const int cc = rc2 % 66, rw = rc2 / 66;
                    const int yr = y0 - 4 + rw, xc = cc - 1;
                    bf16x8 v = {};
                    if ((unsigned)yr < 64u && (unsigned)xc < 64u)
                        v = *(const bf16x8*)(rs + (((size_t)(b * 64 + yr)) * 64 + xc) * 32 + g * 8);
                    *(bf16x8*)(hbuf + (rw * 66 + cc) * 36 + g * 8) = v;
                }
            } else {
                for (int i = tid; i < 2970; i += 1024)
                    *(bf16x8*)(hbuf + i * 8) = (bf16x8){};
            }
        }
        __syncthreads();

        // ---- compute + epilogue (reads xbuf/hbuf; h@t kept in regs) ----
        float hv[2][2][4];
        if (rv) {
            #pragma unroll
            for (int mp = 0; mp < 2; ++mp) {
                f32x4 acc[2][4];
                #pragma unroll
                for (int m2 = 0; m2 < 2; ++m2)
                    #pragma unroll
                    for (int g = 0; g < 4; ++g)
                        acc[m2][g] = (f32x4){bv[g], bv[g], bv[g], bv[g]};

                #pragma unroll
                for (int tap = 0; tap < 9; ++tap) {
                    const int dyk = tap / 3, dxk = tap - dyk * 3;
                    const int bx = ((row + dyk) * 66 + mp * 32 + c + dxk) * 36 + q8;
                    const bf16x8 a0 = *(const bf16x8*)(xbuf + bx);
                    const bf16x8 a1 = *(const bf16x8*)(xbuf + bx + 576);
                    const bf16x8* wpx = wpkv + (size_t)((tap * 2) * 8 + fh * 4) * 64 + L;
                    MFMA8(a0, a1, wpx);
                    const bf16x8 h0 = *(const bf16x8*)(hbuf + bx);
                    const bf16x8 h1v = *(const bf16x8*)(hbuf + bx + 576);
                    const bf16x8* wph = wpkv + (size_t)((tap * 2 + 1) * 8 + fh * 4) * 64 + L;
                    MFMA8(h0, h1v, wph);
                }

                #pragma unroll
                for (int m2 = 0; m2 < 2; ++m2) {
                    #pragma unroll
                    for (int r = 0; r < 4; ++r) {
                        const int px = mp * 32 + m2 * 16 + q * 4 + r;
                        const float ig = fsigmoid(acc[m2][0][r]);
                        const float fg = fsigmoid(acc[m2][1][r]);
                        const float gg = ftanh(acc[m2][2][r]);
                        const float og = fsigmoid(acc[m2][3][r]);
                        const size_t gidx = gbase + (size_t)px * 32 + f;
                        float cold;
                        if (s == 0) cold = firstT ? 0.f : cglob[gidx];
                        else        cold = cbv ? cbuf[(crow * 64 + px) * 32 + f] : 0.f;
                        const float cn = fg * cold + ig * gg;
                        if (cbv) cbuf[(crow * 64 + px) * 32 + f] = cn;
                        const float h_ = og * ftanh(cn);
                        hv[mp][m2][r] = h_;
                        if (own) {
                            if (layer) {
                                out[((size_t)(b * 16 + t) * 4096 + (size_t)yy * 64 + px) * 32 + f] = h_;
                                if (s == 3) { h2w[gidx] = (__bf16)h_; cw[gidx] = cn; }
                            } else {
                                h1buf[(size_t)(t & 7) * PLANE + gidx] = (__bf16)h_;
                                if (s == 3) cw[gidx] = cn;
                            }
                        }
                    }
                }
            }
        }
        __syncthreads();

        // ---- publish h@t into hbuf (in place) for next step ----
        if (s < 3 && rv) {
            #pragma unroll
            for (int mp = 0; mp < 2; ++mp)
                #pragma unroll
                for (int m2 = 0; m2 < 2; ++m2)
                    #pragma unroll
                    for (int r = 0; r < 4; ++r) {
                        const int px = mp * 32 + m2 * 16 + q * 4 + r;
                        hbuf[((row + 1) * 66 + px + 1) * 36 + f] = (__bf16)hv[mp][m2][r];
                    }
        }
    }
}

extern "C" void kernel_launch(void* const* d_in, const int* in_sizes, int n_in,
                              void* d_out, int out_size, void* d_ws, size_t ws_size,
                              hipStream_t stream)
{
    const float* x   = (const float*)d_in[0];
    const float* k1  = (const float*)d_in[1];
    const float* rk1 = (const float*)d_in[2];
    const float* b1  = (const float*)d_in[3];
    const float* k2  = (const float*)d_in[4];
    const float* rk2 = (const float*)d_in[5];
    const float* b2  = (const float*)d_in[6];
    float* out = (float*)d_out;

    __bf16* wpk1  = (__bf16*)d_ws;
    __bf16* wpk2  = wpk1 + WPK_ELEMS;
    __bf16* h1buf = wpk2 + WPK_ELEMS;                     // 8 planes bf16
    __bf16* h2buf = h1buf + 8 * (size_t)PLANE;            // 2 planes bf16
    float*  c1    = (float*)(h2buf + 2 * (size_t)PLANE);  // 2 planes fp32
    float*  c2    = c1 + 2 * (size_t)PLANE;

    pack_weights<<<(2 * WPK_ELEMS + 255) / 256, 256, 0, stream>>>(k1, rk1, k2, rk2, wpk1);

    for (int j = 0; j <= 4; ++j) {
        clstm_s4<<<256, 1024, 0, stream>>>(
            x, wpk1, wpk2, b1, b2, h1buf, h2buf, c1, c2, out, j);
    }
}

// Round 12
// 260.687 us; speedup vs baseline: 4.0204x; 4.0204x over previous
//
#include <hip/hip_runtime.h>

// ConvLSTM2D x2, 2-step temporal blocking, 9 launches, 1024-thr blocks.
// IDENTICAL to the 261us R9 kernel except __launch_bounds__(1024, 1):
// (1024,4) made hipcc budget 64 VGPR/wave (blocks-per-CU semantics) ->
// accumulator scratch spill in every kernel since R9. (1024,1) caps >=128.

typedef __bf16 bf16x8 __attribute__((ext_vector_type(8)));
typedef float f32x4 __attribute__((ext_vector_type(4)));

#define WPK_ELEMS 73728   // per layer: 18 kchunks * 8 ntiles * 64 lanes * 8
#define PLANE 524288      // 4*64*64*32 elems per plane

__device__ __forceinline__ float fsigmoid(float z) {
    return 1.0f / (1.0f + __expf(-z));
}
__device__ __forceinline__ float ftanh(float z) {
    z = fminf(15.0f, fmaxf(-15.0f, z));
    float e = __expf(2.0f * z);
    return (e - 1.0f) / (e + 1.0f);
}

__global__ __launch_bounds__(256) void pack_weights(
    const float* __restrict__ wk1, const float* __restrict__ wr1,
    const float* __restrict__ wk2, const float* __restrict__ wr2,
    __bf16* __restrict__ wpk)
{
    int i = blockIdx.x * 256 + threadIdx.x;
    if (i >= 2 * WPK_ELEMS) return;
    int layer = i / WPK_ELEMS;
    int r = i - layer * WPK_ELEMS;
    int j2 = r & 7;
    int L  = (r >> 3) & 63;
    int nt = (r >> 9) & 7;
    int cix = r >> 12;
    int tap = cix >> 1, src = cix & 1;
    int s = ((L >> 4) << 3) + j2;
    int gate = nt & 3;
    int f = ((nt >> 2) << 4) + (L & 15);
    int n = (gate << 5) + f;
    const float* w = layer ? (src ? wr2 : wk2) : (src ? wr1 : wk1);
    wpk[i] = (__bf16)w[(tap * 32 + s) * 128 + n];
}

__device__ __forceinline__ bf16x8 cvt8(const float* p) {
    const float4 f0 = *(const float4*)p;
    const float4 f1 = *(const float4*)(p + 4);
    bf16x8 v;
    v[0] = (__bf16)f0.x; v[1] = (__bf16)f0.y;
    v[2] = (__bf16)f0.z; v[3] = (__bf16)f0.w;
    v[4] = (__bf16)f1.x; v[5] = (__bf16)f1.y;
    v[6] = (__bf16)f1.z; v[7] = (__bf16)f1.w;
    return v;
}

#define MFMA8(A0, A1, WP)                                                              \
    acc[0][0] = __builtin_amdgcn_mfma_f32_16x16x32_bf16(A0, WP[0],   acc[0][0], 0, 0, 0); \
    acc[0][1] = __builtin_amdgcn_mfma_f32_16x16x32_bf16(A0, WP[64],  acc[0][1], 0, 0, 0); \
    acc[0][2] = __builtin_amdgcn_mfma_f32_16x16x32_bf16(A0, WP[128], acc[0][2], 0, 0, 0); \
    acc[0][3] = __builtin_amdgcn_mfma_f32_16x16x32_bf16(A0, WP[192], acc[0][3], 0, 0, 0); \
    acc[1][0] = __builtin_amdgcn_mfma_f32_16x16x32_bf16(A1, WP[0],   acc[1][0], 0, 0, 0); \
    acc[1][1] = __builtin_amdgcn_mfma_f32_16x16x32_bf16(A1, WP[64],  acc[1][1], 0, 0, 0); \
    acc[1][2] = __builtin_amdgcn_mfma_f32_16x16x32_bf16(A1, WP[128], acc[1][2], 0, 0, 0); \
    acc[1][3] = __builtin_amdgcn_mfma_f32_16x16x32_bf16(A1, WP[192], acc[1][3], 0, 0, 0);

#define MFMA4(A0, WP)                                                                  \
    acc1[0] = __builtin_amdgcn_mfma_f32_16x16x32_bf16(A0, WP[0],   acc1[0], 0, 0, 0);     \
    acc1[1] = __builtin_amdgcn_mfma_f32_16x16x32_bf16(A0, WP[64],  acc1[1], 0, 0, 0);     \
    acc1[2] = __builtin_amdgcn_mfma_f32_16x16x32_bf16(A0, WP[128], acc1[2], 0, 0, 0);     \
    acc1[3] = __builtin_amdgcn_mfma_f32_16x16x32_bf16(A0, WP[192], acc1[3], 0, 0, 0);

__global__ __launch_bounds__(1024, 1) void clstm_pair3(
    const float* __restrict__ x,
    const __bf16* __restrict__ wpk1, const __bf16* __restrict__ wpk2,
    const float* __restrict__ bias1, const float* __restrict__ bias2,
    __bf16* __restrict__ h1buf,       // 4 planes, t%4
    __bf16* __restrict__ h2buf,       // 2 planes (odd t): (t>>1)&1
    float* __restrict__ c1,           // 2 planes (odd t)
    float* __restrict__ c2,
    float* __restrict__ out, int j)
{
    __shared__ __bf16 tXA[6 * 66 * 36];   // step-A input src (x@T0 or h1@T0)
    __shared__ __bf16 tRA[6 * 66 * 36];   // step-A recurrent src (h@T0-1)
    __shared__ __bf16 tXB[4 * 66 * 36];   // step-B input src (x@T0+1 or h1@T0+1)
    __shared__ __bf16 tHA[4 * 66 * 36];   // h@T0 local (zero borders)
    __shared__ float  cpass[2 * 64 * 32]; // c@T0 own rows

    const int blk = blockIdx.x;
    const int k = blk >> 3;
    const int layer = k >> 4;
    if (layer ? (j < 1) : (j > 7)) return;
    const int grp = (blk & 7) * 16 + (k & 15);   // XCD-contiguous rows
    const int T0 = layer ? (2 * j - 2) : (2 * j);
    const int R = grp << 1;
    const int b = R >> 6, y0 = R & 63;

    const int tid = threadIdx.x;
    const int wid = tid >> 6, L = tid & 63;
    const int c = L & 15, q = L >> 4;

    // step-A wave decomposition: (window row, f-half, m-half)
    const int wr  = wid >> 2;
    const int fhA = (wid >> 1) & 1;
    const int mpA = wid & 1;
    const int fA  = fhA * 16 + c;
    // step-B wave decomposition: (own row, f-half, px-quarter)
    const int o   = wid >> 3;
    const int fhB = (wid >> 2) & 1;
    const int pxq = wid & 3;
    const int fB  = fhB * 16 + c;

    const bf16x8* wpkv = (const bf16x8*)(layer ? wpk2 : wpk1);
    const float* bias = layer ? bias2 : bias1;
    float bvA[4], bvB[4];
    #pragma unroll
    for (int g = 0; g < 4; ++g) {
        bvA[g] = bias[g * 32 + fA];
        bvB[g] = bias[g * 32 + fB];
    }

    // ---- staging sources ----
    const float*  xA  = x + (size_t)(b * 16 + T0) * 131072;
    const float*  xB  = xA + 131072;
    const __bf16* h1A = h1buf + (size_t)(T0 & 3) * PLANE;
    const __bf16* h1B = h1buf + (size_t)((T0 + 1) & 3) * PLANE;
    const __bf16* hRA = layer ? (h2buf + (size_t)(((T0 - 1) >> 1) & 1) * PLANE)
                              : (h1buf + (size_t)((T0 - 1) & 3) * PLANE);

    // stage tXA (+ tRA if T0>0): rows y0-2..y0+3
    const int n1 = T0 ? 3168 : 1584;
    for (int i = tid; i < n1; i += 1024) {
        const int tile = (i >= 1584);
        const int r2 = i - tile * 1584;
        const int g = r2 & 3;
        const int rc = r2 >> 2;
        const int cc = rc % 66;
        const int row = rc / 66;
        const int yy = y0 - 2 + row;
        const int xc = cc - 1;
        bf16x8 v = {};
        if (yy >= 0 && yy < 64 && xc >= 0 && xc < 64) {
            if (!layer && !tile) {
                v = cvt8(xA + ((size_t)yy * 64 + xc) * 32 + g * 8);
            } else {
                const __bf16* s = tile ? hRA : h1A;
                v = *(const bf16x8*)(s + (((size_t)(b * 64 + yy)) * 64 + xc) * 32 + g * 8);
            }
        }
        *(bf16x8*)((tile ? tRA : tXA) + (row * 66 + cc) * 36 + g * 8) = v;
    }
    // stage tXB: rows y0-1..y0+2
    for (int i = tid; i < 1056; i += 1024) {
        const int g = i & 3;
        const int rc = i >> 2;
        const int cc = rc % 66;
        const int row = rc / 66;
        const int yy = y0 - 1 + row;
        const int xc = cc - 1;
        bf16x8 v = {};
        if (yy >= 0 && yy < 64 && xc >= 0 && xc < 64) {
            if (!layer) v = cvt8(xB + ((size_t)yy * 64 + xc) * 32 + g * 8);
            else        v = *(const bf16x8*)(h1B + (((size_t)(b * 64 + yy)) * 64 + xc) * 32 + g * 8);
        }
        *(bf16x8*)(tXB + (row * 66 + cc) * 36 + g * 8) = v;
    }
    // zero tHA
    for (int i = tid; i < 1188; i += 1024)
        *(bf16x8*)(tHA + i * 8) = (bf16x8){};
    __syncthreads();

    // ---- step A: h@T0, c@T0 on 4 window rows (y0-1..y0+2), this wave: one
    //      (row, f-half, 32-px half) tile ----
    {
        const int ra = y0 - 1 + wr;
        const bool rvalid = (ra >= 0 && ra < 64);
        const bool own = (wr == 1 || wr == 2);
        const float* crd = (layer ? c2 : c1) + (size_t)(((T0 - 1) >> 1) & 1) * PLANE;
        const size_t rowA = (size_t)(b * 64 + (rvalid ? ra : 0)) * 2048;

        f32x4 acc[2][4];
        #pragma unroll
        for (int m2 = 0; m2 < 2; ++m2)
            #pragma unroll
            for (int g = 0; g < 4; ++g)
                acc[m2][g] = (f32x4){bvA[g], bvA[g], bvA[g], bvA[g]};

        #pragma unroll
        for (int tap = 0; tap < 9; ++tap) {
            const int dyk = tap / 3, dxk = tap % 3;
            const int lb = ((wr + dyk) * 66 + mpA * 32 + c + dxk) * 36 + q * 8;
            const bf16x8 a0 = *(const bf16x8*)(tXA + lb);
            const bf16x8 a1 = *(const bf16x8*)(tXA + lb + 16 * 36);
            const bf16x8* wpx = wpkv + (size_t)((tap * 2) * 8 + fhA * 4) * 64 + L;
            MFMA8(a0, a1, wpx);
            if (T0 > 0) {
                const bf16x8 h0 = *(const bf16x8*)(tRA + lb);
                const bf16x8 h1v = *(const bf16x8*)(tRA + lb + 16 * 36);
                const bf16x8* wph = wpkv + (size_t)((tap * 2 + 1) * 8 + fhA * 4) * 64 + L;
                MFMA8(h0, h1v, wph);
            }
        }
        #pragma unroll
        for (int m2 = 0; m2 < 2; ++m2) {
            #pragma unroll
            for (int r = 0; r < 4; ++r) {
                const int px = mpA * 32 + m2 * 16 + q * 4 + r;
                const float ig = fsigmoid(acc[m2][0][r]);
                const float fg = fsigmoid(acc[m2][1][r]);
                const float gg = ftanh(acc[m2][2][r]);
                const float og = fsigmoid(acc[m2][3][r]);
                float cold = 0.f;
                if (T0 > 0 && rvalid) cold = crd[rowA + (size_t)px * 32 + fA];
                const float cn = (T0 ? fg * cold : 0.f) + ig * gg;
                const float hv = og * ftanh(cn);
                if (rvalid) tHA[(wr * 66 + px + 1) * 36 + fA] = (__bf16)hv;
                if (own) {
                    cpass[(wr - 1) * 2048 + px * 32 + fA] = cn;
                    if (layer)
                        out[((size_t)(b * 16 + T0) * 4096 + (size_t)ra * 64 + px) * 32 + fA] = hv;
                    else
                        h1buf[(size_t)(T0 & 3) * PLANE + rowA + (size_t)px * 32 + fA] = (__bf16)hv;
                }
            }
        }
    }
    __syncthreads();

    // ---- step B: h@T0+1, c@T0+1 on own 2 rows; this wave: one
    //      (own row, f-half, 16-px quarter) tile ----
    {
        const int rb = y0 + o;
        float* cwr = (layer ? c2 : c1) + (size_t)(((T0 + 1) >> 1) & 1) * PLANE;

        f32x4 acc1[4];
        #pragma unroll
        for (int g = 0; g < 4; ++g)
            acc1[g] = (f32x4){bvB[g], bvB[g], bvB[g], bvB[g]};

        #pragma unroll
        for (int tap = 0; tap < 9; ++tap) {
            const int dyk = tap / 3, dxk = tap % 3;
            const int lb = ((o + dyk) * 66 + pxq * 16 + c + dxk) * 36 + q * 8;
            const bf16x8 a0 = *(const bf16x8*)(tXB + lb);
            const bf16x8* wpx = wpkv + (size_t)((tap * 2) * 8 + fhB * 4) * 64 + L;
            MFMA4(a0, wpx);
            const bf16x8 h0 = *(const bf16x8*)(tHA + lb);
            const bf16x8* wph = wpkv + (size_t)((tap * 2 + 1) * 8 + fhB * 4) * 64 + L;
            MFMA4(h0, wph);
        }
        const size_t rowB = (size_t)(b * 64 + rb) * 2048;
        __bf16* h2w = h2buf + (size_t)(((T0 + 1) >> 1) & 1) * PLANE;
        #pragma unroll
        for (int r = 0; r < 4; ++r) {
            const int px = pxq * 16 + q * 4 + r;
            const float ig = fsigmoid(acc1[0][r]);
            const float fg = fsigmoid(acc1[1][r]);
            const float gg = ftanh(acc1[2][r]);
            const float og = fsigmoid(acc1[3][r]);
            const float cold = cpass[o * 2048 + px * 32 + fB];
            const float cn = fg * cold + ig * gg;
            const float hv = og * ftanh(cn);
            cwr[rowB + (size_t)px * 32 + fB] = cn;
            if (layer) {
                out[((size_t)(b * 16 + T0 + 1) * 4096 + (size_t)rb * 64 + px) * 32 + fB] = hv;
                h2w[rowB + (size_t)px * 32 + fB] = (__bf16)hv;
            } else {
                h1buf[(size_t)((T0 + 1) & 3) * PLANE + rowB + (size_t)px * 32 + fB] = (__bf16)hv;
            }
        }
    }
}

extern "C" void kernel_launch(void* const* d_in, const int* in_sizes, int n_in,
                              void* d_out, int out_size, void* d_ws, size_t ws_size,
                              hipStream_t stream)
{
    const float* x   = (const float*)d_in[0];
    const float* k1  = (const float*)d_in[1];
    const float* rk1 = (const float*)d_in[2];
    const float* b1  = (const float*)d_in[3];
    const float* k2  = (const float*)d_in[4];
    const float* rk2 = (const float*)d_in[5];
    const float* b2  = (const float*)d_in[6];
    float* out = (float*)d_out;

    __bf16* wpk1  = (__bf16*)d_ws;
    __bf16* wpk2  = wpk1 + WPK_ELEMS;
    __bf16* h1buf = wpk2 + WPK_ELEMS;             // 4 planes bf16
    __bf16* h2buf = h1buf + 4 * (size_t)PLANE;    // 2 planes bf16
    float*  c1    = (float*)(h2buf + 2 * (size_t)PLANE);  // 2 planes fp32
    float*  c2    = c1 + 2 * (size_t)PLANE;

    pack_weights<<<(2 * WPK_ELEMS + 255) / 256, 256, 0, stream>>>(k1, rk1, k2, rk2, wpk1);

    for (int j = 0; j <= 8; ++j) {
        clstm_pair3<<<256, 1024, 0, stream>>>(
            x, wpk1, wpk2, b1, b2, h1buf, h2buf, c1, c2, out, j);
    }
}